// Round 13
// baseline (147.819 us; speedup 1.0000x reference)
//
#include <hip/hip_runtime.h>
#include <hip/hip_bf16.h>

namespace {

constexpr int HEADS = 4;
constexpr int DQ    = 128;
constexpr int KVB   = 32;
constexpr int QB    = 128;
constexpr int NQT   = 3;               // max len 383 -> 3 q-tiles of 128
constexpr int ROWF  = 3 * DQ * HEADS;  // 1536 floats per token row
constexpr float ALPHA = 0.08838834764831843f;
constexpr float INV_N = 1.0f / 512.0f;

typedef __bf16 bf16x8 __attribute__((ext_vector_type(8)));
typedef float  f32x16 __attribute__((ext_vector_type(16)));
typedef float  f32x4  __attribute__((ext_vector_type(4)));
typedef unsigned int u32;
typedef u32 u32x4 __attribute__((ext_vector_type(4)));

union FragU { u32x4 u; bf16x8 v; };

__device__ __forceinline__ u32 pkbf(float lo, float hi) {
  u32 r;
  asm("v_cvt_pk_bf16_f32 %0, %1, %2" : "=v"(r) : "v"(lo), "v"(hi));
  return r;
}

__device__ __forceinline__ float silu_p(float acc) {
  float s = acc * ALPHA;
  return s * INV_N * __builtin_amdgcn_rcpf(1.0f + __expf(-s));
}

} // namespace

// Block = (qt, b, h): 4 waves, wave w owns q-rows qt*128 + 32w .. +31.
// KVB=32, all-reg staging (pinned) -> bf16 double-buffered LDS (32 KB total)
// -> 3 blocks/CU target via __launch_bounds__(256,3) (regs ~165 unified).
// Round-9 single-barrier pipeline: per phase {compute(t-1) || pack(t);
// issue(t+1); barrier}.
__global__ __launch_bounds__(256, 3)
void hstu_attn_kernel(const float* __restrict__ qkv,
                      const int* __restrict__ seq_offsets,
                      float* __restrict__ out,
                      int Z)
{
  const int xi = blockIdx.x;
  const int qt = (NQT - 1) - xi / Z;          // heavy q-tiles first
  const int b  = (Z - 1) - (xi % Z);          // long sequences first
  const int h  = blockIdx.y;
  const int off = seq_offsets[b];
  const int len = seq_offsets[b + 1] - off;
  if (qt * QB >= len) return;

  __shared__ __align__(16) unsigned short Kb[2][KVB * DQ];   // 2 x 8 KB bf16 [m][d]
  __shared__ __align__(16) unsigned short Vtb[2][KVB * DQ];  // 2 x 8 KB bf16 V^T

  const int t   = threadIdx.x;
  const int l   = t & 63;
  const int l31 = l & 31;
  const int gg  = l >> 5;
  const int nb  = qt * QB + 32 * (t >> 6);   // wave's first q row

  const float* __restrict__ base = qkv + (size_t)off * ROWF + h * (3 * DQ);

  // ---- K staging: thread owns row kr = t>>3, d-range kd0..kd0+15 ----
  const int kr  = t >> 3;          // 0..31
  const int kq  = t & 7;
  const int kd0 = kq * 16;
  f32x4 kraw[4];
  f32x4 vraw[4];

  auto issue_k = [&](int m0) {
    int rm = m0 + kr; rm = rm < len ? rm : len - 1;
    const f32x4* kp = (const f32x4*)(base + (size_t)rm * ROWF + DQ + kd0);
#pragma unroll
    for (int i = 0; i < 4; i++) kraw[i] = kp[i];
#pragma unroll
    for (int i = 0; i < 4; i++) asm volatile("" :: "v"(kraw[i]));  // pin
  };

  auto pack_k = [&](int buf) {
    char* krow = (char*)(Kb[buf]) + kr * 256;
    u32x4 w0, w1;
    w0[0] = pkbf(kraw[0][0], kraw[0][1]);
    w0[1] = pkbf(kraw[0][2], kraw[0][3]);
    w0[2] = pkbf(kraw[1][0], kraw[1][1]);
    w0[3] = pkbf(kraw[1][2], kraw[1][3]);
    w1[0] = pkbf(kraw[2][0], kraw[2][1]);
    w1[1] = pkbf(kraw[2][2], kraw[2][3]);
    w1[2] = pkbf(kraw[3][0], kraw[3][1]);
    w1[3] = pkbf(kraw[3][2], kraw[3][3]);
    int c0 = 2 * kq;
    *(u32x4*)(krow + ((c0 ^ (kr & 15)) << 4))       = w0;
    *(u32x4*)(krow + (((c0 + 1) ^ (kr & 15)) << 4)) = w1;
  };

  // ---- V staging: thread owns rows (m0p, m0p+1), d-range d0v..d0v+7 ----
  const int m0p = (t >> 4) * 2;    // 0..30
  const int d0v = (t & 15) * 8;

  auto issue_v = [&](int m0) {
    int r0 = m0 + m0p;     r0 = r0 < len ? r0 : len - 1;
    int r1 = m0 + m0p + 1; r1 = r1 < len ? r1 : len - 1;
    const f32x4* p0 = (const f32x4*)(base + (size_t)r0 * ROWF + 2 * DQ + d0v);
    const f32x4* p1 = (const f32x4*)(base + (size_t)r1 * ROWF + 2 * DQ + d0v);
    vraw[0] = p0[0]; vraw[1] = p0[1];
    vraw[2] = p1[0]; vraw[3] = p1[1];
#pragma unroll
    for (int i = 0; i < 4; i++) asm volatile("" :: "v"(vraw[i]));  // pin
  };

  auto pack_v = [&](int buf) {
#pragma unroll
    for (int jj = 0; jj < 8; jj++) {
      int d   = d0v + jj;
      int row = d >> 1;
      int ch  = (d & 1) * 4 + (m0p >> 3);
      u32 pv  = pkbf(vraw[jj >> 2][jj & 3], vraw[2 + (jj >> 2)][jj & 3]);
      *(u32*)((char*)(Vtb[buf]) + row * 128 + ((ch ^ (row & 7)) << 4) + (m0p & 7) * 2) = pv;
    }
  };

  issue_k(0);
  issue_v(0);

  // ---- Q fragments (B-operand of swapped QK^T): lane holds Q[n=l31][d=16ks+8gg+j] ----
  bf16x8 qf[8];
  {
    int n  = nb + l31;
    int rq = n < len ? n : len - 1;   // clamped rows never stored
    const float* qrow = base + (size_t)rq * ROWF;
#pragma unroll
    for (int ks = 0; ks < 8; ks++) {
      int d = ks * 16 + gg * 8;
      f32x4 a0 = *(const f32x4*)(qrow + d);
      f32x4 a1 = *(const f32x4*)(qrow + d + 4);
      FragU u;
      u.u[0] = pkbf(a0[0], a0[1]);
      u.u[1] = pkbf(a0[2], a0[3]);
      u.u[2] = pkbf(a1[0], a1[1]);
      u.u[3] = pkbf(a1[2], a1[3]);
      qf[ks] = u.v;
    }
  }

  f32x16 Of[4];
#pragma unroll
  for (int i = 0; i < 4; i++)
#pragma unroll
    for (int r = 0; r < 16; r++) Of[i][r] = 0.0f;

  // ---- per-tile compute: QK^T -> silu -> permlane swap -> PV ----
  auto compute = [&](int kvt) {
    const int m0  = kvt * KVB;
    const int buf = kvt & 1;
    if (nb < len && m0 <= nb + 31) {   // wave-uniform causal skip
      const bool needmask = (m0 + KVB - 1) > nb;

      // QK^T: S^T tile 32m x 32n (single fragment at KVB=32)
      f32x16 acc;
#pragma unroll
      for (int r = 0; r < 16; r++) acc[r] = 0.0f;
      const char* krow = (const char*)(Kb[buf]) + l31 * 256;
      const int   ksw  = l31 & 15;
      __builtin_amdgcn_s_setprio(1);
#pragma unroll
      for (int ks = 0; ks < 8; ks++) {
        int cb = 2 * ks + gg;   // chunk = d/8, d = 16ks+8gg
        bf16x8 kb = *(const bf16x8*)(krow + ((cb ^ ksw) << 4));
        // S^T = K * Q^T : lane holds n=l31, m=(r&3)+8(r>>2)+4gg
        acc = __builtin_amdgcn_mfma_f32_32x32x16_bf16(kb, qf[ks], acc, 0, 0, 0);
      }
      __builtin_amdgcn_s_setprio(0);

      // silu + causal mask, pack bf16 pairs (m, m+1)
      u32 wk[8];
#pragma unroll
      for (int i = 0; i < 8; i++) {
        int r  = 2 * i;
        int mr = m0 + (r & 3) + 8 * (r >> 2) + 4 * gg;
        float p0 = silu_p(acc[r]);
        float p1 = silu_p(acc[r + 1]);
        if (needmask) {
          int nglob = nb + l31;
          if (mr > nglob)     p0 = 0.0f;
          if (mr + 1 > nglob) p1 = 0.0f;
        }
        wk[i] = pkbf(p0, p1);
      }

      // redistribute halves lane<->lane+32 via permlane32_swap
      bf16x8 pa[2];
      {
        FragU fa, fb;
        fa.u[0] = wk[0]; fa.u[1] = wk[1]; fa.u[2] = wk[2]; fa.u[3] = wk[3];
        fb.u[0] = wk[4]; fb.u[1] = wk[5]; fb.u[2] = wk[6]; fb.u[3] = wk[7];
        asm("v_permlane32_swap_b32 %0, %1" : "+v"(fa.u[0]), "+v"(fa.u[2]));
        asm("v_permlane32_swap_b32 %0, %1" : "+v"(fa.u[1]), "+v"(fa.u[3]));
        asm("v_permlane32_swap_b32 %0, %1" : "+v"(fb.u[0]), "+v"(fb.u[2]));
        asm("v_permlane32_swap_b32 %0, %1" : "+v"(fb.u[1]), "+v"(fb.u[3]));
        pa[0] = fa.v;   // m 0..15
        pa[1] = fb.v;   // m 16..31
      }

      // PV: O += P * V^T (A = P frags in reg, B = V^T from LDS)
      __builtin_amdgcn_s_setprio(1);
#pragma unroll
      for (int ks = 0; ks < 2; ks++) {
#pragma unroll
        for (int dt = 0; dt < 4; dt++) {
          int d   = dt * 32 + l31;
          int row = d >> 1;
          int ch  = (d & 1) * 4 + (2 * ks + gg);   // m>>3 = 2ks+gg
          bf16x8 vb = *(const bf16x8*)((char*)(Vtb[buf]) + row * 128 + ((ch ^ (row & 7)) << 4));
          Of[dt] = __builtin_amdgcn_mfma_f32_32x32x16_bf16(pa[ks], vb, Of[dt], 0, 0, 0);
        }
      }
      __builtin_amdgcn_s_setprio(0);
    }
  };

  const int nkv = min((len + KVB - 1) >> 5, 4 * qt + 4);

  for (int kvt = 0; kvt < nkv; kvt++) {
    // compute previous tile first: MFMAs issue before the pack's vmcnt wait.
    if (kvt > 0) compute(kvt - 1);

    pack_k(kvt & 1);                 // vmcnt waits kraw, writes buf[kvt&1]
    pack_v(kvt & 1);                 // waits vraw
    if (kvt + 1 < nkv) {
      issue_k((kvt + 1) * KVB);      // next-tile loads fly across the barrier
      issue_v((kvt + 1) * KVB);
    }
    asm volatile("s_waitcnt lgkmcnt(0)" ::: "memory");
    __builtin_amdgcn_s_barrier();    // single barrier per tile
    __builtin_amdgcn_sched_barrier(0);
  }
  compute(nkv - 1);                  // tail

  // ---- epilogue: coalesced 4B stores for rows n < len ----
#pragma unroll
  for (int dt = 0; dt < 4; dt++) {
    int d = dt * 32 + l31;
#pragma unroll
    for (int r = 0; r < 16; r++) {
      int nloc = 4 * gg + (r & 3) + 8 * (r >> 2);
      int n = nb + nloc;
      if (n < len)
        out[(size_t)(off + n) * (HEADS * DQ) + h * DQ + d] = Of[dt][r];
    }
  }
}

extern "C" void kernel_launch(void* const* d_in, const int* in_sizes, int n_in,
                              void* d_out, int out_size, void* d_ws, size_t ws_size,
                              hipStream_t stream) {
  const float* qkv         = (const float*)d_in[0];
  const int*   seq_offsets = (const int*)d_in[1];
  float*       out         = (float*)d_out;
  int Z = in_sizes[1] - 1;
  dim3 grid(NQT * Z, HEADS);
  hstu_attn_kernel<<<grid, dim3(256), 0, stream>>>(qkv, seq_offsets, out, Z);
}

// Round 14
// 87.096 us; speedup vs baseline: 1.6972x; 1.6972x over previous
//
#include <hip/hip_runtime.h>
#include <hip/hip_bf16.h>

namespace {

constexpr int HEADS = 4;
constexpr int DQ    = 128;
constexpr int KVB   = 64;
constexpr int QB    = 128;
constexpr int NQT   = 3;               // max len 383 -> 3 q-tiles of 128
constexpr int ROWF  = 3 * DQ * HEADS;  // 1536 floats per token row
constexpr float ALPHA = 0.08838834764831843f;
constexpr float INV_N = 1.0f / 512.0f;

typedef __bf16 bf16x8 __attribute__((ext_vector_type(8)));
typedef float  f32x16 __attribute__((ext_vector_type(16)));
typedef float  f32x4  __attribute__((ext_vector_type(4)));
typedef unsigned int u32;
typedef u32 u32x4 __attribute__((ext_vector_type(4)));

union FragU { u32x4 u; bf16x8 v; };

__device__ __forceinline__ u32 pkbf(float lo, float hi) {
  u32 r;
  asm("v_cvt_pk_bf16_f32 %0, %1, %2" : "=v"(r) : "v"(lo), "v"(hi));
  return r;
}

__device__ __forceinline__ float silu_p(float acc) {
  float s = acc * ALPHA;
  return s * INV_N * __builtin_amdgcn_rcpf(1.0f + __expf(-s));
}

} // namespace

// Block = (qt, b, h): 4 waves, wave w owns q-rows qt*128 + 32w .. +31.
// K,V reg-staged depth-1 (pinned) -> bf16 double-buffered LDS. One barrier
// per tile; compute(t-1) overlaps pack(t). Issue order pack_k -> issue_k ->
// pack_v -> issue_v: pack_v waits vmcnt(8) (in-order retire), so K(t+1)
// stays in flight through the barrier into compute(t).
__global__ __launch_bounds__(256, 2)
void hstu_attn_kernel(const float* __restrict__ qkv,
                      const int* __restrict__ seq_offsets,
                      float* __restrict__ out,
                      int Z)
{
  const int xi = blockIdx.x;
  const int qt = (NQT - 1) - xi / Z;          // heavy q-tiles first
  const int b  = (Z - 1) - (xi % Z);          // long sequences first
  const int h  = blockIdx.y;
  const int off = seq_offsets[b];
  const int len = seq_offsets[b + 1] - off;
  if (qt * QB >= len) return;

  __shared__ __align__(16) unsigned short Kb[2][KVB * DQ];   // 2 x 16 KB bf16 [m][d]
  __shared__ __align__(16) unsigned short Vtb[2][KVB * DQ];  // 2 x 16 KB bf16 V^T

  const int t   = threadIdx.x;
  const int l   = t & 63;
  const int l31 = l & 31;
  const int gg  = l >> 5;
  const int nb  = qt * QB + 32 * (t >> 6);   // wave's first q row

  const float* __restrict__ base = qkv + (size_t)off * ROWF + h * (3 * DQ);

  // ---- K staging: thread owns row kr = t>>2, chunks {kq+4i} (8 floats each) ----
  const int kr  = t >> 2;
  const int kq  = t & 3;
  f32x4 kraw[8];
  f32x4 vraw[8];

  auto issue_k = [&](int m0) {
    int rm = m0 + kr; rm = rm < len ? rm : len - 1;
    const float* kp = base + (size_t)rm * ROWF + DQ;
#pragma unroll
    for (int i = 0; i < 4; i++) {
      const f32x4* p = (const f32x4*)(kp + (kq + 4 * i) * 8);
      kraw[2 * i]     = p[0];
      kraw[2 * i + 1] = p[1];
    }
#pragma unroll
    for (int i = 0; i < 8; i++) asm volatile("" :: "v"(kraw[i]));  // pin
  };

  auto pack_k = [&](int buf) {
    char* krow = (char*)(Kb[buf]) + kr * 256;
#pragma unroll
    for (int i = 0; i < 4; i++) {
      u32x4 wv;
      wv[0] = pkbf(kraw[2 * i][0], kraw[2 * i][1]);
      wv[1] = pkbf(kraw[2 * i][2], kraw[2 * i][3]);
      wv[2] = pkbf(kraw[2 * i + 1][0], kraw[2 * i + 1][1]);
      wv[3] = pkbf(kraw[2 * i + 1][2], kraw[2 * i + 1][3]);
      int c = kq + 4 * i;
      *(u32x4*)(krow + ((c ^ (kr & 15)) << 4)) = wv;
    }
  };

  // ---- V staging: thread owns rows (m0p, m0p+1), d-range d0v..d0v+15 ----
  const int m0p = (t >> 3) * 2;
  const int d0v = (t & 7) * 16;

  auto issue_v = [&](int m0) {
    int r0 = m0 + m0p;     r0 = r0 < len ? r0 : len - 1;
    int r1 = m0 + m0p + 1; r1 = r1 < len ? r1 : len - 1;
    const f32x4* p0 = (const f32x4*)(base + (size_t)r0 * ROWF + 2 * DQ + d0v);
    const f32x4* p1 = (const f32x4*)(base + (size_t)r1 * ROWF + 2 * DQ + d0v);
#pragma unroll
    for (int i = 0; i < 4; i++) { vraw[i] = p0[i]; vraw[4 + i] = p1[i]; }
#pragma unroll
    for (int i = 0; i < 8; i++) asm volatile("" :: "v"(vraw[i]));  // pin
  };

  auto pack_v = [&](int buf) {
#pragma unroll
    for (int jj = 0; jj < 16; jj++) {
      int d   = d0v + jj;
      int row = d >> 1;
      int ch  = (d & 1) * 8 + (m0p >> 3);
      u32 pv  = pkbf(vraw[jj >> 2][jj & 3], vraw[4 + (jj >> 2)][jj & 3]);
      *(u32*)((char*)(Vtb[buf]) + row * 256 + ((ch ^ (row & 15)) << 4) + (m0p & 7) * 2) = pv;
    }
  };

  issue_k(0);
  issue_v(0);

  // ---- Q fragments (B-operand of swapped QK^T): lane holds Q[n=l31][d=16ks+8gg+j] ----
  bf16x8 qf[8];
  {
    int n  = nb + l31;
    int rq = n < len ? n : len - 1;   // clamped rows never stored
    const float* qrow = base + (size_t)rq * ROWF;
#pragma unroll
    for (int ks = 0; ks < 8; ks++) {
      int d = ks * 16 + gg * 8;
      f32x4 a0 = *(const f32x4*)(qrow + d);
      f32x4 a1 = *(const f32x4*)(qrow + d + 4);
      FragU u;
      u.u[0] = pkbf(a0[0], a0[1]);
      u.u[1] = pkbf(a0[2], a0[3]);
      u.u[2] = pkbf(a1[0], a1[1]);
      u.u[3] = pkbf(a1[2], a1[3]);
      qf[ks] = u.v;
    }
  }

  f32x16 Of[4];
#pragma unroll
  for (int i = 0; i < 4; i++)
#pragma unroll
    for (int r = 0; r < 16; r++) Of[i][r] = 0.0f;

  // ---- per-tile compute: QK^T -> silu -> permlane swap -> PV ----
  auto compute = [&](int kvt) {
    const int m0  = kvt * KVB;
    const int buf = kvt & 1;
    if (nb < len && m0 <= nb + 31) {   // wave-uniform causal skip
      const bool needmask = (m0 + KVB - 1) > nb;
      bf16x8 pa[4];

#pragma unroll
      for (int mt = 0; mt < 2; mt++) {
        f32x16 acc;
#pragma unroll
        for (int r = 0; r < 16; r++) acc[r] = 0.0f;
        const int mrow = mt * 32 + l31;
        const char* krow = (const char*)(Kb[buf]) + mrow * 256;
        const int   ksw  = mrow & 15;
        __builtin_amdgcn_s_setprio(1);
#pragma unroll
        for (int ks = 0; ks < 8; ks++) {
          int cb = 2 * ks + gg;   // chunk = d/8, d = 16ks+8gg
          bf16x8 kb = *(const bf16x8*)(krow + ((cb ^ ksw) << 4));
          // S^T = K * Q^T : lane holds n=l31, m=(r&3)+8(r>>2)+4gg+32mt
          acc = __builtin_amdgcn_mfma_f32_32x32x16_bf16(kb, qf[ks], acc, 0, 0, 0);
        }
        __builtin_amdgcn_s_setprio(0);

        // silu + causal mask, pack bf16 pairs (m, m+1)
        u32 wk[8];
#pragma unroll
        for (int i = 0; i < 8; i++) {
          int r  = 2 * i;
          int mr = m0 + (r & 3) + 8 * (r >> 2) + 4 * gg + 32 * mt;
          float p0 = silu_p(acc[r]);
          float p1 = silu_p(acc[r + 1]);
          if (needmask) {
            int nglob = nb + l31;
            if (mr > nglob)     p0 = 0.0f;
            if (mr + 1 > nglob) p1 = 0.0f;
          }
          wk[i] = pkbf(p0, p1);
        }

        // redistribute halves lane<->lane+32 via permlane32_swap
        FragU fa, fb;
        fa.u[0] = wk[0]; fa.u[1] = wk[1]; fa.u[2] = wk[2]; fa.u[3] = wk[3];
        fb.u[0] = wk[4]; fb.u[1] = wk[5]; fb.u[2] = wk[6]; fb.u[3] = wk[7];
        asm("v_permlane32_swap_b32 %0, %1" : "+v"(fa.u[0]), "+v"(fa.u[2]));
        asm("v_permlane32_swap_b32 %0, %1" : "+v"(fa.u[1]), "+v"(fa.u[3]));
        asm("v_permlane32_swap_b32 %0, %1" : "+v"(fb.u[0]), "+v"(fb.u[2]));
        asm("v_permlane32_swap_b32 %0, %1" : "+v"(fb.u[1]), "+v"(fb.u[3]));
        pa[2 * mt]     = fa.v;
        pa[2 * mt + 1] = fb.v;
      }

      // PV: O += P * V^T (A = P frags in reg, B = V^T from LDS)
      __builtin_amdgcn_s_setprio(1);
#pragma unroll
      for (int ks = 0; ks < 4; ks++) {
#pragma unroll
        for (int dt = 0; dt < 4; dt++) {
          int d   = dt * 32 + l31;
          int row = d >> 1;
          int ch  = (d & 1) * 8 + (2 * ks + gg);   // m>>3 = 2ks+gg
          bf16x8 vb = *(const bf16x8*)((char*)(Vtb[buf]) + row * 256 + ((ch ^ (row & 15)) << 4));
          Of[dt] = __builtin_amdgcn_mfma_f32_32x32x16_bf16(pa[ks], vb, Of[dt], 0, 0, 0);
        }
      }
      __builtin_amdgcn_s_setprio(0);
    }
  };

  const int nkv = min((len + KVB - 1) >> 6, 2 * qt + 2);

  // ---- phase 0 (peeled: no compute) ----
  pack_k(0);                         // vmcnt waits kraw(0)
  if (1 < nkv) issue_k(KVB);         // kraw free; K(1) in flight early
  pack_v(0);                         // vmcnt(8): K(1) stays in flight
  if (1 < nkv) issue_v(KVB);
  asm volatile("s_waitcnt lgkmcnt(0)" ::: "memory");
  __builtin_amdgcn_s_barrier();
  __builtin_amdgcn_sched_barrier(0);

  for (int kvt = 1; kvt < nkv; kvt++) {
    compute(kvt - 1);                // MFMAs issue before this phase's vmcnt wait

    pack_k(kvt & 1);                 // vmcnt(8): waits kraw(kvt) only
    if (kvt + 1 < nkv) issue_k((kvt + 1) * KVB);
    pack_v(kvt & 1);                 // vmcnt(8): K(kvt+1) stays in flight
    if (kvt + 1 < nkv) issue_v((kvt + 1) * KVB);
    asm volatile("s_waitcnt lgkmcnt(0)" ::: "memory");
    __builtin_amdgcn_s_barrier();    // single barrier per tile
    __builtin_amdgcn_sched_barrier(0);
  }
  compute(nkv - 1);                  // tail

  // ---- epilogue: coalesced 4B stores for rows n < len ----
#pragma unroll
  for (int dt = 0; dt < 4; dt++) {
    int d = dt * 32 + l31;
#pragma unroll
    for (int r = 0; r < 16; r++) {
      int nloc = 4 * gg + (r & 3) + 8 * (r >> 2);
      int n = nb + nloc;
      if (n < len)
        out[(size_t)(off + n) * (HEADS * DQ) + h * DQ + d] = Of[dt][r];
    }
  }
}

extern "C" void kernel_launch(void* const* d_in, const int* in_sizes, int n_in,
                              void* d_out, int out_size, void* d_ws, size_t ws_size,
                              hipStream_t stream) {
  const float* qkv         = (const float*)d_in[0];
  const int*   seq_offsets = (const int*)d_in[1];
  float*       out         = (float*)d_out;
  int Z = in_sizes[1] - 1;
  dim3 grid(NQT * Z, HEADS);
  hstu_attn_kernel<<<grid, dim3(256), 0, stream>>>(qkv, seq_offsets, out, Z);
}